// Round 6
// baseline (383.890 us; speedup 1.0000x reference)
//
#include <hip/hip_runtime.h>
#include <hip/hip_bf16.h>
#include <cstdint>
#include <cstddef>

#define B_DIM 4096
#define IN_F 4096
#define OUT_F 4096
#define NNZ_N 1677722

typedef short short8 __attribute__((ext_vector_type(8)));
typedef float floatx4 __attribute__((ext_vector_type(4)));
typedef unsigned short ushort8 __attribute__((ext_vector_type(8)));

// ---------------------------------------------------------------------------
// f32 -> bf16 RNE
// ---------------------------------------------------------------------------
__device__ inline unsigned short f2bf(float f) {
  union { float f; unsigned int u; } v;
  v.f = f;
  unsigned int u = v.u;
  return (unsigned short)((u + 0x7fffu + ((u >> 16) & 1u)) >> 16);
}

// ---------------------------------------------------------------------------
// Atomic-free densification. History:
//  R1-R4: 1.67M device atomics (any flavor) = ~150us — per-line RMW rate.
//  R5: 105K reservation atomics on 32 hot lines = ~same 150us (3.3K
//      serialized RMWs/line x ~50ns). Lesson: device atomics are the enemy.
//  Now: deterministic slots. seg[blk][bucket][slot], MAXPER=56 slots/cell
//  (cell count ~Binom(8192,1/512): mean 16, max over 105K cells ~35; 56 is
//  +10 sigma, clamp-guarded). P1: ONE pass, LDS cursors only, plain stores.
//  P2: one block per bucket, flat predicated slot walk, LDS f32 row-image,
//  bf16 rows out. Zero global atomics, zero memsets.
// ---------------------------------------------------------------------------
#define P1_CHUNK 8192
#define P1_BLOCKS ((NNZ_N + P1_CHUNK - 1) / P1_CHUNK)  // 205
#define NBUCK 512                                      // 8 rows per bucket
#define MAXPER 56
#define CVT_BLOCKS ((B_DIM * IN_F) / 8 / 256)          // 8192

__global__ __launch_bounds__(256) void p1_bucket_cvt(
    const float* __restrict__ vals, const int* __restrict__ rows,
    const int* __restrict__ cols, unsigned int* __restrict__ cntmat,
    unsigned long long* __restrict__ seg, const float* __restrict__ x,
    unsigned short* __restrict__ xb) {
  __shared__ unsigned int cur[NBUCK];
  const int b = blockIdx.x;
  if (b < P1_BLOCKS) {
    for (int i = threadIdx.x; i < NBUCK; i += 256) cur[i] = 0;
    __syncthreads();
    const int base = b * P1_CHUNK;
#pragma unroll
    for (int j = 0; j < P1_CHUNK / 256; ++j) {
      int idx = base + j * 256 + threadIdx.x;
      if (idx < NNZ_N) {
        int r = rows[idx];
        int c = cols[idx];
        float v = vals[idx];
        int bk = r >> 3;
        unsigned int pos = atomicAdd(&cur[bk], 1u);  // LDS ds_add_rtn_u32
        if (pos < MAXPER) {
          union {
            struct { unsigned int k; float v; } s;
            unsigned long long u;
          } e;
          e.s.k = (((unsigned int)(r & 7)) << 12) | (unsigned int)c;
          e.s.v = v;
          seg[((size_t)b * NBUCK + bk) * MAXPER + pos] = e.u;
        }
      }
    }
    __syncthreads();
    for (int i = threadIdx.x; i < NBUCK; i += 256) {
      unsigned int n = cur[i];
      cntmat[b * NBUCK + i] = n > MAXPER ? MAXPER : n;
    }
  } else {
    size_t i = ((size_t)(b - P1_BLOCKS) * 256 + threadIdx.x) * 8;
    float4 a = *(const float4*)(x + i);
    float4 f = *(const float4*)(x + i + 4);
    ushort8 o;
    o[0] = f2bf(a.x); o[1] = f2bf(a.y); o[2] = f2bf(a.z); o[3] = f2bf(a.w);
    o[4] = f2bf(f.x); o[5] = f2bf(f.y); o[6] = f2bf(f.z); o[7] = f2bf(f.w);
    *(ushort8*)(xb + i) = o;
  }
}

__global__ __launch_bounds__(256) void p2_accum(
    const unsigned int* __restrict__ cntmat,
    const unsigned long long* __restrict__ seg,
    unsigned short* __restrict__ wb) {
  __shared__ float img[8 * 4096];           // 128 KB f32 image of 8 rows
  __shared__ unsigned short cnt[P1_BLOCKS]; // per-source-block fill counts
  const int b = blockIdx.x;
  floatx4* img4 = (floatx4*)img;
  for (int i = threadIdx.x; i < 8192; i += 256) img4[i] = (floatx4)0.0f;
  for (int i = threadIdx.x; i < P1_BLOCKS; i += 256)
    cnt[i] = (unsigned short)cntmat[i * NBUCK + b];
  __syncthreads();
  const int TOT = P1_BLOCKS * MAXPER;  // 11480 slots
  for (int s = threadIdx.x; s < TOT; s += 256) {
    int blk = s / MAXPER;
    int slot = s - blk * MAXPER;
    if (slot < (int)cnt[blk]) {
      unsigned long long e = seg[((size_t)blk * NBUCK + b) * MAXPER + slot];
      union { unsigned int u; float f; } v;
      v.u = (unsigned int)(e >> 32);
      atomicAdd(&img[(unsigned int)e & 0x7FFFu], v.f);  // LDS ds_add_f32
    }
  }
  __syncthreads();
  unsigned short* dst = wb + (size_t)b * 8 * 4096;
  for (int i = threadIdx.x; i < 4096; i += 256) {
    floatx4 a = img4[i * 2];
    floatx4 f = img4[i * 2 + 1];
    ushort8 o;
    o[0] = f2bf(a[0]); o[1] = f2bf(a[1]); o[2] = f2bf(a[2]); o[3] = f2bf(a[3]);
    o[4] = f2bf(f[0]); o[5] = f2bf(f[1]); o[6] = f2bf(f[2]); o[7] = f2bf(f[3]);
    *(ushort8*)(dst + i * 8) = o;
  }
}

// ---------------------------------------------------------------------------
// bf16 MFMA GEMM, C = A * B^T + bias  (unchanged from R2: m97-structure
// plateau, 128x128 tile, BK=64, XOR-swizzled LDS — conflicts measured 0)
// ---------------------------------------------------------------------------
__device__ inline void load_lds16(const unsigned short* g,
                                  const unsigned short* lds_base) {
  __builtin_amdgcn_global_load_lds(
      (const __attribute__((address_space(1))) unsigned int*)g,
      (__attribute__((address_space(3))) unsigned int*)lds_base, 16, 0, 0);
}

__global__ __launch_bounds__(256) void gemm_bt_bf16(
    const unsigned short* __restrict__ A, const unsigned short* __restrict__ Bt,
    const float* __restrict__ bias, float* __restrict__ C) {
  __shared__ unsigned short lA[128 * 64];  // [row][k] XOR-swizzled, unpadded
  __shared__ unsigned short lB[128 * 64];

  const int tid = threadIdx.x;
  const int wid = tid >> 6;
  const int lane = tid & 63;

  const int bm0 = blockIdx.y * 128;
  const int bn0 = blockIdx.x * 128;

  const int wm = (wid >> 1) * 64;
  const int wn = (wid & 1) * 64;

  floatx4 acc[4][4];
#pragma unroll
  for (int i = 0; i < 4; ++i)
#pragma unroll
    for (int j = 0; j < 4; ++j) acc[i][j] = (floatx4)0.0f;

  const int ldr = lane >> 3;
  const int ldc = ((lane & 7) ^ (ldr & 7)) * 8;

  const unsigned short* gA = A + (size_t)(bm0 + wid * 32) * IN_F;
  const unsigned short* gB = Bt + (size_t)(bn0 + wid * 32) * IN_F;

  for (int k0 = 0; k0 < IN_F; k0 += 64) {
#pragma unroll
    for (int j = 0; j < 4; ++j) {
      load_lds16(gA + (size_t)(j * 8 + ldr) * IN_F + k0 + ldc,
                 &lA[(wid * 32 + j * 8) * 64]);
      load_lds16(gB + (size_t)(j * 8 + ldr) * IN_F + k0 + ldc,
                 &lB[(wid * 32 + j * 8) * 64]);
    }
    __syncthreads();

    const int rr = lane & 15;
    const int rx = rr & 7;
    const int kq = lane >> 4;
#pragma unroll
    for (int ks = 0; ks < 2; ++ks) {
      const int kchunk = ks * 4 + kq;
      const int kcs = ((kchunk ^ rx) << 3);
      short8 af[4], bf[4];
#pragma unroll
      for (int i = 0; i < 4; ++i)
        af[i] = *(const short8*)&lA[(wm + i * 16 + rr) * 64 + kcs];
#pragma unroll
      for (int j = 0; j < 4; ++j)
        bf[j] = *(const short8*)&lB[(wn + j * 16 + rr) * 64 + kcs];
#pragma unroll
      for (int i = 0; i < 4; ++i)
#pragma unroll
        for (int j = 0; j < 4; ++j)
          acc[i][j] = __builtin_amdgcn_mfma_f32_16x16x32_bf16(
              af[i], bf[j], acc[i][j], 0, 0, 0);
    }
    __syncthreads();
  }

  const int cn = lane & 15;
  const int r0 = (lane >> 4) * 4;
#pragma unroll
  for (int j = 0; j < 4; ++j) {
    const int col = bn0 + wn + j * 16 + cn;
    const float bv = bias[col];
#pragma unroll
    for (int i = 0; i < 4; ++i) {
#pragma unroll
      for (int r = 0; r < 4; ++r) {
        const int row = bm0 + wm + i * 16 + r0 + r;
        C[(size_t)row * OUT_F + col] = acc[i][j][r] + bv;
      }
    }
  }
}

// ---------------------------------------------------------------------------
extern "C" void kernel_launch(void* const* d_in, const int* in_sizes, int n_in,
                              void* d_out, int out_size, void* d_ws,
                              size_t ws_size, hipStream_t stream) {
  const float* x = (const float*)d_in[0];
  const float* vals = (const float*)d_in[1];
  const int* rows = (const int*)d_in[2];
  const int* cols = (const int*)d_in[3];
  const float* bias = (const float*)d_in[4];
  float* out = (float*)d_out;

  // ws: cntmat 420KB @0 | seg ~45MB @1MB | wb 32MB @48MB | xb 32MB @80MB
  unsigned int* cntmat = (unsigned int*)d_ws;
  unsigned long long* seg =
      (unsigned long long*)((char*)d_ws + ((size_t)1 << 20));
  unsigned short* wb = (unsigned short*)((char*)d_ws + ((size_t)48 << 20));
  unsigned short* xb = (unsigned short*)((char*)d_ws + ((size_t)80 << 20));

  p1_bucket_cvt<<<P1_BLOCKS + CVT_BLOCKS, 256, 0, stream>>>(
      vals, rows, cols, cntmat, seg, x, xb);
  p2_accum<<<NBUCK, 256, 0, stream>>>(cntmat, seg, wb);

  dim3 grid(OUT_F / 128, B_DIM / 128);
  gemm_bt_bf16<<<grid, 256, 0, stream>>>(xb, wb, bias, out);
}